// Round 1
// baseline (258.869 us; speedup 1.0000x reference)
//
#include <hip/hip_runtime.h>
#include <stdint.h>

#define B 256
#define DIM 512
#define TOPK 4096
#define MARGIN 0.2f

// ---------------- ws layout ----------------
// D      : float [256*256]     @ 0        (262144 B)
// hist   : u32   [2048]        @ 262144   (8192 B)
// state  : u32   [2]           @ 270336   (prefix/T_bits, needed)
// part   : double[256]         @ 270352
// total ~272.4 KB

__global__ void init_kernel(uint32_t* __restrict__ hist, uint32_t* __restrict__ state) {
    int tid = threadIdx.x;
    for (int i = tid; i < 2048; i += 256) hist[i] = 0;
    if (tid == 0) { state[0] = 0u; state[1] = (uint32_t)TOPK; }
}

__global__ void dist_kernel(const float* __restrict__ x, float* __restrict__ Dm) {
    __shared__ float xi[DIM];
    const int i = blockIdx.x;
    const int tid = threadIdx.x;
    for (int k = tid; k < DIM; k += 256) xi[k] = x[i * DIM + k];
    __syncthreads();
    const int j = tid;
    const float4* xj4 = (const float4*)(x + j * DIM);
    float acc = 0.f;
#pragma unroll 4
    for (int k4 = 0; k4 < DIM / 4; ++k4) {
        float4 b = xj4[k4];
        float d0 = xi[k4 * 4 + 0] - b.x;
        float d1 = xi[k4 * 4 + 1] - b.y;
        float d2 = xi[k4 * 4 + 2] - b.z;
        float d3 = xi[k4 * 4 + 3] - b.w;
        acc += d0 * d0 + d1 * d1 + d2 * d2 + d3 * d3;
    }
    Dm[i * B + j] = acc;
}

// PASS 0: bucket = bits[31:21] (2048), no prefix check
// PASS 1: bucket = bits[20:10] (2048), check bits[31:21] == prefix
// PASS 2: bucket = bits[ 9: 0] (1024), check bits[31:10] == prefix
template <int PASS>
__global__ void hist_kernel(const float* __restrict__ Dm, const int* __restrict__ lab,
                            uint32_t* __restrict__ ghist, const uint32_t* __restrict__ state) {
    __shared__ float    sD[B];
    __shared__ int      sL[B];
    __shared__ uint32_t sh[2048];
    const int q   = blockIdx.x;
    const int tid = threadIdx.x;
    for (int i = tid; i < 2048; i += 256) sh[i] = 0;
    sD[tid] = Dm[q * B + tid];
    sL[tid] = lab[tid];
    __syncthreads();

    const int      lq     = sL[q];
    const uint32_t prefix = state[0];
    const bool  nvalid = (sL[tid] != lq);
    const float dqn    = sD[tid];

    for (int p = 0; p < q; ++p) {
        if (sL[p] != lq) continue;          // uniform branch (LDS broadcast)
        const float base = sD[p] + MARGIN;
        if (nvalid) {
            const float    v    = fmaxf(base - dqn, 0.0f);
            const uint32_t bits = __float_as_uint(v);
            if (PASS == 0) {
                atomicAdd(&sh[bits >> 21], 1u);
            } else if (PASS == 1) {
                if ((bits >> 21) == prefix) atomicAdd(&sh[(bits >> 10) & 0x7FFu], 1u);
            } else {
                if ((bits >> 10) == prefix) atomicAdd(&sh[bits & 0x3FFu], 1u);
            }
        }
    }
    __syncthreads();
    for (int i = tid; i < 2048; i += 256) {
        uint32_t c = sh[i];
        if (c) atomicAdd(&ghist[i], c);
    }
}

template <int PASS>
__global__ void select_kernel(uint32_t* __restrict__ hist, uint32_t* __restrict__ state) {
    const int tid = threadIdx.x;
    if (tid == 0) {
        const uint32_t needed = state[1];
        uint32_t cum = 0;
        const int nb = (PASS == 2) ? 1024 : 2048;
        int sel = 0;
        for (int b = nb - 1; b >= 0; --b) {
            const uint32_t h = hist[b];
            if (cum + h >= needed) { sel = b; break; }
            cum += h;
        }
        state[1] = needed - cum;            // how many == current prefix still needed
        uint32_t prefix = state[0];
        if (PASS == 0)      prefix = (uint32_t)sel;
        else if (PASS == 1) prefix = (prefix << 11) | (uint32_t)sel;
        else                prefix = (prefix << 10) | (uint32_t)sel;  // full T bits
        state[0] = prefix;
    }
    __syncthreads();
    for (int i = tid; i < 2048; i += 256) hist[i] = 0;   // ready for next pass
}

__global__ void sum_kernel(const float* __restrict__ Dm, const int* __restrict__ lab,
                           const uint32_t* __restrict__ state, double* __restrict__ part) {
    __shared__ float  sD[B];
    __shared__ int    sL[B];
    __shared__ double wsum[4];
    const int q   = blockIdx.x;
    const int tid = threadIdx.x;
    sD[tid] = Dm[q * B + tid];
    sL[tid] = lab[tid];
    __syncthreads();

    const int      lq = sL[q];
    const uint32_t T  = state[0];
    const bool  nvalid = (sL[tid] != lq);
    const float dqn    = sD[tid];

    double acc = 0.0;
    for (int p = 0; p < q; ++p) {
        if (sL[p] != lq) continue;
        const float base = sD[p] + MARGIN;
        if (nvalid) {
            const float v = fmaxf(base - dqn, 0.0f);
            if (__float_as_uint(v) > T) acc += (double)v;
        }
    }
    // wave (64-lane) reduce, then cross-wave via LDS — deterministic
#pragma unroll
    for (int off = 32; off > 0; off >>= 1) acc += __shfl_down(acc, off);
    if ((tid & 63) == 0) wsum[tid >> 6] = acc;
    __syncthreads();
    if (tid == 0) part[q] = wsum[0] + wsum[1] + wsum[2] + wsum[3];
}

__global__ void final_kernel(const double* __restrict__ part, const uint32_t* __restrict__ state,
                             float* __restrict__ out) {
    if (threadIdx.x == 0) {
        double s = 0.0;
        for (int i = 0; i < B; ++i) s += part[i];
        const float    tv     = __uint_as_float(state[0]);
        const uint32_t needed = state[1];
        s += (double)needed * (double)tv;
        out[0] = (float)(s / (double)TOPK);
    }
}

extern "C" void kernel_launch(void* const* d_in, const int* in_sizes, int n_in,
                              void* d_out, int out_size, void* d_ws, size_t ws_size,
                              hipStream_t stream) {
    const float* x   = (const float*)d_in[0];
    const int*   lab = (const int*)d_in[1];
    float*       out = (float*)d_out;

    char* ws = (char*)d_ws;
    float*    Dm    = (float*)ws;
    uint32_t* hist  = (uint32_t*)(ws + 262144);
    uint32_t* state = (uint32_t*)(ws + 270336);
    double*   part  = (double*)(ws + 270352);

    init_kernel<<<1, 256, 0, stream>>>(hist, state);
    dist_kernel<<<B, 256, 0, stream>>>(x, Dm);

    hist_kernel<0><<<B, 256, 0, stream>>>(Dm, lab, hist, state);
    select_kernel<0><<<1, 256, 0, stream>>>(hist, state);
    hist_kernel<1><<<B, 256, 0, stream>>>(Dm, lab, hist, state);
    select_kernel<1><<<1, 256, 0, stream>>>(hist, state);
    hist_kernel<2><<<B, 256, 0, stream>>>(Dm, lab, hist, state);
    select_kernel<2><<<1, 256, 0, stream>>>(hist, state);

    sum_kernel<<<B, 256, 0, stream>>>(Dm, lab, state, part);
    final_kernel<<<1, 64, 0, stream>>>(part, state, out);
}

// Round 2
// 126.094 us; speedup vs baseline: 2.0530x; 2.0530x over previous
//
#include <hip/hip_runtime.h>
#include <stdint.h>

#define B 256
#define DIM 512
#define TOPK 4096
#define MARGIN 0.2f

// ---------------- ws layout ----------------
// D      : float [256*256]     @ 0        (262144 B)
// hist   : u32   [2048]        @ 262144   (8192 B)
// state  : u32   [2]           @ 270336   (prefix/T_bits, needed)
// part   : double[256]         @ 270352
// total ~272.4 KB

// dist + init fused: block 0 additionally zeroes hist and seeds state.
__global__ void dist_kernel(const float* __restrict__ x, float* __restrict__ Dm,
                            uint32_t* __restrict__ hist, uint32_t* __restrict__ state) {
    __shared__ float xi[DIM];
    const int i = blockIdx.x;
    const int tid = threadIdx.x;
    if (i == 0) {
        for (int k = tid; k < 2048; k += 256) hist[k] = 0;
        if (tid == 0) { state[0] = 0u; state[1] = (uint32_t)TOPK; }
    }
    for (int k = tid; k < DIM; k += 256) xi[k] = x[i * DIM + k];
    __syncthreads();
    const int j = tid;
    const float4* xj4 = (const float4*)(x + j * DIM);
    float acc = 0.f;
#pragma unroll 4
    for (int k4 = 0; k4 < DIM / 4; ++k4) {
        float4 b = xj4[k4];
        float d0 = xi[k4 * 4 + 0] - b.x;
        float d1 = xi[k4 * 4 + 1] - b.y;
        float d2 = xi[k4 * 4 + 2] - b.z;
        float d3 = xi[k4 * 4 + 3] - b.w;
        acc += d0 * d0 + d1 * d1 + d2 * d2 + d3 * d3;
    }
    Dm[i * B + j] = acc;
}

// PASS 0: bucket = bits[31:21] (2048), no prefix check
// PASS 1: bucket = bits[20:10] (2048), check bits[31:21] == prefix
// PASS 2: bucket = bits[ 9: 0] (1024), check bits[31:10] == prefix
template <int PASS>
__global__ void hist_kernel(const float* __restrict__ Dm, const int* __restrict__ lab,
                            uint32_t* __restrict__ ghist, const uint32_t* __restrict__ state) {
    __shared__ float    sD[B];
    __shared__ int      sL[B];
    __shared__ uint32_t sh[2048];
    const int q   = blockIdx.x;
    const int tid = threadIdx.x;
    for (int i = tid; i < 2048; i += 256) sh[i] = 0;
    sD[tid] = Dm[q * B + tid];
    sL[tid] = lab[tid];
    __syncthreads();

    const int      lq     = sL[q];
    const uint32_t prefix = state[0];
    const bool  nvalid = (sL[tid] != lq);
    const float dqn    = sD[tid];

    for (int p = 0; p < q; ++p) {
        if (sL[p] != lq) continue;          // uniform branch (LDS broadcast)
        const float base = sD[p] + MARGIN;
        if (nvalid) {
            const float    v    = fmaxf(base - dqn, 0.0f);
            const uint32_t bits = __float_as_uint(v);
            if (PASS == 0) {
                atomicAdd(&sh[bits >> 21], 1u);
            } else if (PASS == 1) {
                if ((bits >> 21) == prefix) atomicAdd(&sh[(bits >> 10) & 0x7FFu], 1u);
            } else {
                if ((bits >> 10) == prefix) atomicAdd(&sh[bits & 0x3FFu], 1u);
            }
        }
    }
    __syncthreads();
    for (int i = tid; i < 2048; i += 256) {
        uint32_t c = sh[i];
        if (c) atomicAdd(&ghist[i], c);
    }
}

// Parallel selection: cooperative LDS staging + chunk sums; the serial part is
// ~256 LDS iterations (chunk scan) + <=8 (intra-chunk), not 2048 global loads.
// Also zeroes hist for the next pass.
template <int PASS>
__global__ void select_kernel(uint32_t* __restrict__ hist, uint32_t* __restrict__ state) {
    const int nb  = (PASS == 2) ? 1024 : 2048;
    const int per = nb / 256;                 // buckets per thread (8 or 4)
    __shared__ uint32_t sv[2048];
    __shared__ uint32_t csum[256];
    const int tid = threadIdx.x;
    uint32_t local = 0;
    for (int k = 0; k < per; ++k) {
        const int b = tid * per + k;
        const uint32_t h = hist[b];
        sv[b] = h;
        local += h;
        hist[b] = 0;                          // ready for next pass
    }
    csum[tid] = local;
    __syncthreads();
    if (tid == 0) {
        const uint32_t needed = state[1];
        uint32_t cum = 0;
        int c = 255;
        for (; c > 0; --c) {
            if (cum + csum[c] >= needed) break;
            cum += csum[c];
        }
        int sel = c * per;
        for (int b = (c + 1) * per - 1; b >= c * per; --b) {
            const uint32_t h = sv[b];
            if (cum + h >= needed) { sel = b; break; }
            cum += h;
        }
        state[1] = needed - cum;              // how many == current prefix still needed
        uint32_t prefix = state[0];
        if (PASS == 0)      prefix = (uint32_t)sel;
        else if (PASS == 1) prefix = (prefix << 11) | (uint32_t)sel;
        else                prefix = (prefix << 10) | (uint32_t)sel;  // full T bits
        state[0] = prefix;
    }
}

__global__ void sum_kernel(const float* __restrict__ Dm, const int* __restrict__ lab,
                           const uint32_t* __restrict__ state, double* __restrict__ part) {
    __shared__ float  sD[B];
    __shared__ int    sL[B];
    __shared__ double wsum[4];
    const int q   = blockIdx.x;
    const int tid = threadIdx.x;
    sD[tid] = Dm[q * B + tid];
    sL[tid] = lab[tid];
    __syncthreads();

    const int      lq = sL[q];
    const uint32_t T  = state[0];
    const bool  nvalid = (sL[tid] != lq);
    const float dqn    = sD[tid];

    double acc = 0.0;
    for (int p = 0; p < q; ++p) {
        if (sL[p] != lq) continue;
        const float base = sD[p] + MARGIN;
        if (nvalid) {
            const float v = fmaxf(base - dqn, 0.0f);
            if (__float_as_uint(v) > T) acc += (double)v;
        }
    }
    // wave (64-lane) reduce, then cross-wave via LDS — deterministic
#pragma unroll
    for (int off = 32; off > 0; off >>= 1) acc += __shfl_down(acc, off);
    if ((tid & 63) == 0) wsum[tid >> 6] = acc;
    __syncthreads();
    if (tid == 0) part[q] = wsum[0] + wsum[1] + wsum[2] + wsum[3];
}

__global__ void final_kernel(const double* __restrict__ part, const uint32_t* __restrict__ state,
                             float* __restrict__ out) {
    if (threadIdx.x == 0) {
        double s = 0.0;
        for (int i = 0; i < B; ++i) s += part[i];
        const float    tv     = __uint_as_float(state[0]);
        const uint32_t needed = state[1];
        s += (double)needed * (double)tv;
        out[0] = (float)(s / (double)TOPK);
    }
}

extern "C" void kernel_launch(void* const* d_in, const int* in_sizes, int n_in,
                              void* d_out, int out_size, void* d_ws, size_t ws_size,
                              hipStream_t stream) {
    const float* x   = (const float*)d_in[0];
    const int*   lab = (const int*)d_in[1];
    float*       out = (float*)d_out;

    char* ws = (char*)d_ws;
    float*    Dm    = (float*)ws;
    uint32_t* hist  = (uint32_t*)(ws + 262144);
    uint32_t* state = (uint32_t*)(ws + 270336);
    double*   part  = (double*)(ws + 270352);

    dist_kernel<<<B, 256, 0, stream>>>(x, Dm, hist, state);

    hist_kernel<0><<<B, 256, 0, stream>>>(Dm, lab, hist, state);
    select_kernel<0><<<1, 256, 0, stream>>>(hist, state);
    hist_kernel<1><<<B, 256, 0, stream>>>(Dm, lab, hist, state);
    select_kernel<1><<<1, 256, 0, stream>>>(hist, state);
    hist_kernel<2><<<B, 256, 0, stream>>>(Dm, lab, hist, state);
    select_kernel<2><<<1, 256, 0, stream>>>(hist, state);

    sum_kernel<<<B, 256, 0, stream>>>(Dm, lab, state, part);
    final_kernel<<<1, 64, 0, stream>>>(part, state, out);
}